// Round 9
// baseline (757.954 us; speedup 1.0000x reference)
//
#include <hip/hip_runtime.h>
#include <hip/hip_cooperative_groups.h>
#include <math.h>

#define N_NODES 50000
#define N_EDGES 800000
#define DIM_IN 64
#define DIM_HID 128
#define DIM_OUT 64
#define NTILES 6250   // 800000 / 128 edges per tile

typedef __attribute__((ext_vector_type(8))) short short8;   // 8 bf16 (4 VGPRs)
typedef __attribute__((ext_vector_type(4))) float f32x4;    // MFMA accumulator

union U8 { uint4 u; short8 s; };

// RTNE float->bf16 (inputs finite)
__device__ __forceinline__ unsigned short f2bf(float f) {
    unsigned u = __float_as_uint(f);
    return (unsigned short)((u + 0x7fffu + ((u >> 16) & 1u)) >> 16);
}

__device__ __forceinline__ unsigned cvt_pk_bf16(float a, float b) {
#if __has_builtin(__builtin_amdgcn_cvt_pk_bf16_f32)
    auto pk = __builtin_amdgcn_cvt_pk_bf16_f32(a, b);   // lo=a, hi=b
    unsigned d; __builtin_memcpy(&d, &pk, 4);
    return d;
#else
    return (unsigned)f2bf(a) | ((unsigned)f2bf(b) << 16);
#endif
}

__device__ __forceinline__ float exp2_fast(float a) {
#if __has_builtin(__builtin_amdgcn_exp2f)
    return __builtin_amdgcn_exp2f(a);
#else
    return __expf(a * 0.69314718f);
#endif
}

// softplus(x) = max(x,0) + log1p(exp(-|x|)); cubic log1p fit, err ~1.5e-3
__device__ __forceinline__ unsigned sp2(float x0, float x1) {
    const float L2E = 1.44269504f;
    float z0 = exp2_fast(-fabsf(x0) * L2E);
    float z1 = exp2_fast(-fabsf(x1) * L2E);
    float p0 = fmaf(fmaf(fmaf(-0.1011458f, z0, 0.2942925f), z0, -0.5f), z0, 1.0f) * z0;
    float p1 = fmaf(fmaf(fmaf(-0.1011458f, z1, 0.2942925f), z1, -0.5f), z1, 1.0f) * z1;
    return cvt_pk_bf16(fmaxf(x0, 0.0f) + p0, fmaxf(x1, 0.0f) + p1);
}

// Single cooperative kernel:
//   phase 1: zero `out`; convert W0,W1,W2 -> bf16 W^T compact [row][128]
//            (layers 1,2 K-permuted by pi(s) - proven rounds 4-8)
//   grid.sync()
//   phase 2: persistent grid-stride over 6250 tiles, round-5 proven MLP body:
//     layers 0,1 flipped: mfma(A=weight, B=activation); C col=l16=edge,
//       row=q*4+r=feature -> lane keeps its own edges' features; inter-layer
//       transform = softplus + cvt_pk + register renaming (pi in weights).
//     layer 2 un-flipped: C row=edge, col=feature -> coalesced 64B atomics.
//   No LDS, no block barriers in phase 2; 60-VGPR-class body for max occupancy.
__global__ __launch_bounds__(256, 4)
void fused_mlp(const float* __restrict__ x,
               const int* __restrict__ eidx,
               const float* __restrict__ W0, const float* __restrict__ b0,
               const float* __restrict__ W1, const float* __restrict__ b1,
               const float* __restrict__ W2, const float* __restrict__ b2,
               unsigned short* __restrict__ wt,
               float* __restrict__ out) {
    const int gtid = blockIdx.x * 256 + threadIdx.x;
    const int T = gridDim.x * 256;

    // ---- phase 1a: zero the output (atomic targets) ----
    float4 z4 = make_float4(0.f, 0.f, 0.f, 0.f);
    float4* o4 = (float4*)out;
    for (int i = gtid; i < (N_NODES * DIM_OUT) / 4; i += T) o4[i] = z4;

    // ---- phase 1b: weights -> bf16 compact W^T [row][128] ----
    for (int i = gtid; i < 320 * 128; i += T) {
        int row = i >> 7, s = i & 127;
        int f = ((s >> 5) << 5) | (((s & 7) >> 2) << 4) | (((s >> 3) & 3) << 2) | (s & 3);
        float v;
        if (row < 128)      v = W0[s * DIM_HID + row];          // layer 0: natural k
        else if (row < 256) v = W1[f * DIM_HID + (row - 128)];  // layer 1: permuted k
        else                v = W2[f * DIM_OUT + (row - 256)];  // layer 2: permuted k
        wt[i] = f2bf(v);
    }

    __threadfence();                      // device-scope visibility across XCDs
    cooperative_groups::this_grid().sync();

    // ---- phase 2: persistent MLP over edge tiles ----
    const int lane = threadIdx.x & 63;
    const int w    = threadIdx.x >> 6;
    const int l16  = lane & 15;
    const int q    = lane >> 4;

    const unsigned short* Wt0 = wt;
    const unsigned short* Wt1 = wt + 128 * 128;
    const unsigned short* Wt2 = wt + 256 * 128;

#pragma unroll 1
    for (int tile = blockIdx.x; tile < NTILES; tile += gridDim.x) {
        const int e0w = tile * 128 + w * 32;   // this wave's 32 edges

        int nodeR[2], nodeC[2];
#pragma unroll
        for (int m = 0; m < 2; ++m) {
            nodeR[m] = eidx[e0w + m * 16 + l16];
            nodeC[m] = eidx[N_EDGES + e0w + m * 16 + l16];
        }

        // layer-0 B-frags straight from x: B(k=kk*32+q*8+j, edge=m*16+l16)
        short8 hfr[2][4];
#pragma unroll
        for (int m = 0; m < 2; ++m)
#pragma unroll
            for (int kk = 0; kk < 4; ++kk) {
                int node = (kk >= 2) ? nodeC[m] : nodeR[m];
                const float* p = x + ((size_t)node << 6) + ((kk & 1) << 5) + (q << 3);
                float4 v0 = *(const float4*)p;
                float4 v1 = *(const float4*)(p + 4);
                U8 t;
                t.u.x = cvt_pk_bf16(v0.x, v0.y);
                t.u.y = cvt_pk_bf16(v0.z, v0.w);
                t.u.z = cvt_pk_bf16(v1.x, v1.y);
                t.u.w = cvt_pk_bf16(v1.z, v1.w);
                hfr[m][kk] = t.s;
            }

        // ---- layers 0,1 (flipped): H^T = softplus(W^T H^T + b) ----
#pragma unroll
        for (int L = 0; L < 2; ++L) {
            const unsigned short* W = L ? Wt1 : Wt0;
            const float* bias = L ? b1 : b0;
            unsigned d[2][8][2];
#pragma unroll
            for (int ti = 0; ti < 8; ++ti) {
                f32x4 bb = *(const f32x4*)(bias + ti * 16 + q * 4);  // bias on row dim
                f32x4 a0 = bb, a1 = bb;
                const unsigned short* Wp = W + ((ti * 16 + l16) << 7) + q * 8;
#pragma unroll
                for (int kk = 0; kk < 4; ++kk) {
                    short8 wf = *(const short8*)(Wp + kk * 32);
                    a0 = __builtin_amdgcn_mfma_f32_16x16x32_bf16(wf, hfr[0][kk], a0, 0, 0, 0);
                    a1 = __builtin_amdgcn_mfma_f32_16x16x32_bf16(wf, hfr[1][kk], a1, 0, 0, 0);
                }
                d[0][ti][0] = sp2(a0[0], a0[1]);
                d[0][ti][1] = sp2(a0[2], a0[3]);
                d[1][ti][0] = sp2(a1[0], a1[1]);
                d[1][ti][1] = sp2(a1[2], a1[3]);
            }
            // next-layer frags: pure register renaming (weights carry pi)
#pragma unroll
            for (int m = 0; m < 2; ++m)
#pragma unroll
                for (int kk = 0; kk < 4; ++kk) {
                    U8 t;
                    t.u.x = d[m][2 * kk][0];
                    t.u.y = d[m][2 * kk][1];
                    t.u.z = d[m][2 * kk + 1][0];
                    t.u.w = d[m][2 * kk + 1][1];
                    hfr[m][kk] = t.s;
                }
        }

        // ---- layer 2 (un-flipped): O = H W2 + b2; C row=edge, col=feature ----
        int nodeO[2][4];
#pragma unroll
        for (int m = 0; m < 2; ++m)
#pragma unroll
            for (int r = 0; r < 4; ++r)
                nodeO[m][r] = eidx[e0w + m * 16 + q * 4 + r];   // L1-hot reload

#pragma unroll
        for (int ti = 0; ti < 4; ++ti) {
            float bv = b2[ti * 16 + l16];                        // bias on col dim
            f32x4 a0 = (f32x4){bv, bv, bv, bv};
            f32x4 a1 = a0;
            const unsigned short* Wp = Wt2 + ((ti * 16 + l16) << 7) + q * 8;
#pragma unroll
            for (int kk = 0; kk < 4; ++kk) {
                short8 wf = *(const short8*)(Wp + kk * 32);
                a0 = __builtin_amdgcn_mfma_f32_16x16x32_bf16(hfr[0][kk], wf, a0, 0, 0, 0);
                a1 = __builtin_amdgcn_mfma_f32_16x16x32_bf16(hfr[1][kk], wf, a1, 0, 0, 0);
            }
#pragma unroll
            for (int r = 0; r < 4; ++r) {
                atomicAdd(out + ((size_t)nodeO[0][r] << 6) + ti * 16 + l16, a0[r]);
                atomicAdd(out + ((size_t)nodeO[1][r] << 6) + ti * 16 + l16, a1[r]);
            }
        }
    }
}

extern "C" void kernel_launch(void* const* d_in, const int* in_sizes, int n_in,
                              void* d_out, int out_size, void* d_ws, size_t ws_size,
                              hipStream_t stream) {
    const float* x  = (const float*)d_in[0];
    const int*   ei = (const int*)d_in[1];
    const float* W0 = (const float*)d_in[2];
    const float* b0 = (const float*)d_in[3];
    const float* W1 = (const float*)d_in[4];
    const float* b1 = (const float*)d_in[5];
    const float* W2 = (const float*)d_in[6];
    const float* b2 = (const float*)d_in[7];
    float* out = (float*)d_out;
    unsigned short* wt = (unsigned short*)d_ws;   // 81920 bytes used

    // co-residency-guaranteed grid size (deterministic per call; host-side query
    // only - no alloc/sync, graph-capture-safe)
    int maxb = 0;
    hipOccupancyMaxActiveBlocksPerMultiprocessor(&maxb, (const void*)fused_mlp, 256, 0);
    if (maxb < 1) maxb = 1;
    if (maxb > 8) maxb = 8;                       // 8 blocks/CU = 32 waves/CU cap
    int grid = maxb * 256;

    void* args[] = {(void*)&x, (void*)&ei,
                    (void*)&W0, (void*)&b0, (void*)&W1, (void*)&b1,
                    (void*)&W2, (void*)&b2, (void*)&wt, (void*)&out};
    hipLaunchCooperativeKernel((const void*)fused_mlp, dim3(grid), dim3(256),
                               args, 0, stream);
}

// Round 10
// 413.624 us; speedup vs baseline: 1.8325x; 1.8325x over previous
//
#include <hip/hip_runtime.h>
#include <math.h>

#define N_NODES 50000
#define N_EDGES 800000
#define DIM_IN 64
#define DIM_HID 128
#define DIM_OUT 64
#define NT2 3125   // 800000 / 256 edges per tile

typedef __attribute__((ext_vector_type(8))) short short8;   // 8 bf16 (4 VGPRs)
typedef __attribute__((ext_vector_type(4))) float f32x4;    // MFMA accumulator

union U8 { uint4 u; short8 s; };

// RTNE float->bf16 (inputs finite)
__device__ __forceinline__ unsigned short f2bf(float f) {
    unsigned u = __float_as_uint(f);
    return (unsigned short)((u + 0x7fffu + ((u >> 16) & 1u)) >> 16);
}

__device__ __forceinline__ unsigned cvt_pk_bf16(float a, float b) {
#if __has_builtin(__builtin_amdgcn_cvt_pk_bf16_f32)
    auto pk = __builtin_amdgcn_cvt_pk_bf16_f32(a, b);   // lo=a, hi=b
    unsigned d; __builtin_memcpy(&d, &pk, 4);
    return d;
#else
    return (unsigned)f2bf(a) | ((unsigned)f2bf(b) << 16);
#endif
}

__device__ __forceinline__ float exp2_fast(float a) {
#if __has_builtin(__builtin_amdgcn_exp2f)
    return __builtin_amdgcn_exp2f(a);
#else
    return __expf(a * 0.69314718f);
#endif
}

// softplus(x) = max(x,0) + log1p(exp(-|x|)); cubic log1p fit, err ~1.5e-3
__device__ __forceinline__ unsigned sp2(float x0, float x1) {
    const float L2E = 1.44269504f;
    float z0 = exp2_fast(-fabsf(x0) * L2E);
    float z1 = exp2_fast(-fabsf(x1) * L2E);
    float p0 = fmaf(fmaf(fmaf(-0.1011458f, z0, 0.2942925f), z0, -0.5f), z0, 1.0f) * z0;
    float p1 = fmaf(fmaf(fmaf(-0.1011458f, z1, 0.2942925f), z1, -0.5f), z1, 1.0f) * z1;
    return cvt_pk_bf16(fmaxf(x0, 0.0f) + p0, fmaxf(x1, 0.0f) + p1);
}

// Fused prep: blocks [0,160) convert weights -> bf16 compact W^T [row][128]
// (layers 1,2 K-permuted by pi(s), proven rounds 4-9); blocks [160,12660) zero out.
__global__ void prep_zero(const float* __restrict__ W0,
                          const float* __restrict__ W1,
                          const float* __restrict__ W2,
                          unsigned short* __restrict__ wt,
                          float4* __restrict__ out4) {
    if (blockIdx.x < 160) {
        int i = blockIdx.x * 256 + threadIdx.x;      // < 40960 = 320*128
        int row = i >> 7, s = i & 127;
        int f = ((s >> 5) << 5) | (((s & 7) >> 2) << 4) | (((s >> 3) & 3) << 2) | (s & 3);
        float v;
        if (row < 128)      v = W0[s * DIM_HID + row];          // layer 0: natural k
        else if (row < 256) v = W1[f * DIM_HID + (row - 128)];  // layer 1: permuted k
        else                v = W2[f * DIM_OUT + (row - 256)];  // layer 2: permuted k
        wt[i] = f2bf(v);
    } else {
        int i = (blockIdx.x - 160) * 256 + threadIdx.x;
        if (i < (N_NODES * DIM_OUT) / 4)
            out4[i] = make_float4(0.f, 0.f, 0.f, 0.f);
    }
}

// Round-5 proven MLP body widened to M=4 (64 edges/wave, 256-edge tiles):
//   layers 0,1 flipped: mfma(A=weight, B=activation); C col=l16=edge,
//     row=q*4+r=feature; inter-layer transform = softplus + cvt_pk + register
//     renaming (K-permutation pi folded into the weights).
//   layer 2 un-flipped: C row=q*4+r=edge, col=l16-based feature -> coalesced
//     64B atomic sectors.
// Each wf weight fragment now feeds 4 back-to-back independent MFMAs (was 2):
// halves per-edge weight traffic, doubles load-latency-hiding ILP.
__global__ __launch_bounds__(256, 3)
void edge_mlp_m4(const float* __restrict__ x,
                 const int* __restrict__ eidx,
                 const unsigned short* __restrict__ wt,
                 const float* __restrict__ b0,
                 const float* __restrict__ b1,
                 const float* __restrict__ b2,
                 float* __restrict__ out) {
    const int lane = threadIdx.x & 63;
    const int w    = threadIdx.x >> 6;
    const int l16  = lane & 15;
    const int q    = lane >> 4;
    const int e0w  = blockIdx.x * 256 + w * 64;   // this wave's 64 edges

    const unsigned short* Wt0 = wt;
    const unsigned short* Wt1 = wt + 128 * 128;
    const unsigned short* Wt2 = wt + 256 * 128;

    int nodeR[4], nodeC[4];
#pragma unroll
    for (int m = 0; m < 4; ++m) {
        nodeR[m] = eidx[e0w + m * 16 + l16];
        nodeC[m] = eidx[N_EDGES + e0w + m * 16 + l16];
    }

    // layer-0 B-frags straight from x: B(k=kk*32+q*8+j, edge=m*16+l16)
    short8 hfr[4][4];
#pragma unroll
    for (int m = 0; m < 4; ++m)
#pragma unroll
        for (int kk = 0; kk < 4; ++kk) {
            int node = (kk >= 2) ? nodeC[m] : nodeR[m];
            const float* p = x + ((size_t)node << 6) + ((kk & 1) << 5) + (q << 3);
            float4 v0 = *(const float4*)p;
            float4 v1 = *(const float4*)(p + 4);
            U8 t;
            t.u.x = cvt_pk_bf16(v0.x, v0.y);
            t.u.y = cvt_pk_bf16(v0.z, v0.w);
            t.u.z = cvt_pk_bf16(v1.x, v1.y);
            t.u.w = cvt_pk_bf16(v1.z, v1.w);
            hfr[m][kk] = t.s;
        }

    // ---- layers 0,1 (flipped): H^T = softplus(W^T H^T + b) ----
#pragma unroll
    for (int L = 0; L < 2; ++L) {
        const unsigned short* W = L ? Wt1 : Wt0;
        const float* bias = L ? b1 : b0;
        unsigned d[4][8][2];
#pragma unroll
        for (int ti = 0; ti < 8; ++ti) {
            f32x4 bb = *(const f32x4*)(bias + ti * 16 + q * 4);  // bias on row dim
            f32x4 acc[4];
#pragma unroll
            for (int m = 0; m < 4; ++m) acc[m] = bb;
            const unsigned short* Wp = W + ((ti * 16 + l16) << 7) + q * 8;
#pragma unroll
            for (int kk = 0; kk < 4; ++kk) {
                short8 wf = *(const short8*)(Wp + kk * 32);
#pragma unroll
                for (int m = 0; m < 4; ++m)
                    acc[m] = __builtin_amdgcn_mfma_f32_16x16x32_bf16(
                        wf, hfr[m][kk], acc[m], 0, 0, 0);
            }
#pragma unroll
            for (int m = 0; m < 4; ++m) {
                d[m][ti][0] = sp2(acc[m][0], acc[m][1]);
                d[m][ti][1] = sp2(acc[m][2], acc[m][3]);
            }
        }
        // next-layer frags: pure register renaming (weights carry pi)
#pragma unroll
        for (int m = 0; m < 4; ++m)
#pragma unroll
            for (int kk = 0; kk < 4; ++kk) {
                U8 t;
                t.u.x = d[m][2 * kk][0];
                t.u.y = d[m][2 * kk][1];
                t.u.z = d[m][2 * kk + 1][0];
                t.u.w = d[m][2 * kk + 1][1];
                hfr[m][kk] = t.s;
            }
    }

    // ---- layer 2 (un-flipped): O = H W2 + b2; C row=edge, col=feature ----
    int nodeO[4][4];
#pragma unroll
    for (int m = 0; m < 4; ++m)
#pragma unroll
        for (int r = 0; r < 4; ++r)
            nodeO[m][r] = eidx[e0w + m * 16 + q * 4 + r];   // L1-hot reload

#pragma unroll
    for (int ti = 0; ti < 4; ++ti) {
        float bv = b2[ti * 16 + l16];                        // bias on col dim
        f32x4 acc[4];
#pragma unroll
        for (int m = 0; m < 4; ++m) acc[m] = (f32x4){bv, bv, bv, bv};
        const unsigned short* Wp = Wt2 + ((ti * 16 + l16) << 7) + q * 8;
#pragma unroll
        for (int kk = 0; kk < 4; ++kk) {
            short8 wf = *(const short8*)(Wp + kk * 32);
#pragma unroll
            for (int m = 0; m < 4; ++m)
                acc[m] = __builtin_amdgcn_mfma_f32_16x16x32_bf16(
                    hfr[m][kk], wf, acc[m], 0, 0, 0);
        }
#pragma unroll
        for (int m = 0; m < 4; ++m)
#pragma unroll
            for (int r = 0; r < 4; ++r)
                atomicAdd(out + ((size_t)nodeO[m][r] << 6) + ti * 16 + l16, acc[m][r]);
    }
}

extern "C" void kernel_launch(void* const* d_in, const int* in_sizes, int n_in,
                              void* d_out, int out_size, void* d_ws, size_t ws_size,
                              hipStream_t stream) {
    const float* x  = (const float*)d_in[0];
    const int*   ei = (const int*)d_in[1];
    const float* W0 = (const float*)d_in[2];
    const float* b0 = (const float*)d_in[3];
    const float* W1 = (const float*)d_in[4];
    const float* b1 = (const float*)d_in[5];
    const float* W2 = (const float*)d_in[6];
    const float* b2 = (const float*)d_in[7];
    float* out = (float*)d_out;
    unsigned short* wt = (unsigned short*)d_ws;   // 81920 bytes used

    // one prep dispatch: weights (160 blocks) + out zeroing (12500 blocks)
    prep_zero<<<160 + (N_NODES * DIM_OUT / 4 + 255) / 256, 256, 0, stream>>>(
        W0, W1, W2, wt, (float4*)out);

    edge_mlp_m4<<<NT2, 256, 0, stream>>>(x, ei, wt, b0, b1, b2, out);
}